// Round 9
// baseline (98.012 us; speedup 1.0000x reference)
//
#include <hip/hip_runtime.h>

typedef __attribute__((ext_vector_type(8))) short bf16x8;
typedef __attribute__((ext_vector_type(4))) float f32x4;
typedef __attribute__((ext_vector_type(8))) unsigned short u16x8;
typedef __attribute__((ext_vector_type(2))) unsigned u32x2;

#define DM 2048
#define DI 4096
#define BATCH 128

__device__ __forceinline__ unsigned short f2bf(float f) {
  union { float f; unsigned u; } v; v.f = f;
  unsigned r = v.u + 0x7FFFu + ((v.u >> 16) & 1u);
  return (unsigned short)(r >> 16);
}
__device__ __forceinline__ float bf2f(unsigned short u) {
  union { unsigned u; float f; } v; v.u = (unsigned)u << 16; return v.f;
}
// packed f32x2 -> bf16x2 (1 VALU inst, HW RNE)
__device__ __forceinline__ unsigned pk2bf(float lo, float hi) {
  unsigned r;
  asm("v_cvt_pk_bf16_f32 %0, %1, %2" : "=v"(r) : "v"(lo), "v"(hi));
  return r;
}
__device__ __forceinline__ float sigm(float x) { return 1.f / (1.f + __expf(-x)); }

// ---- depth-2 software-pipelined GEMM, 256 threads = 4 waves (2M x 2N) ----
// BK=32 variant: LDS per block halved vs BK=64 -> 4+ blocks/CU resident.
// Wave tile = (BM/2) x (BN/2). D row = m0 + wm*(BM/2)+mi*16+(lane>>4)*4+r,
// col = n0 + wn*16*NF + ni*16 + (lane&15).
// Named register sets (compile-time indexing); ldregs(t+2) before compute(t),
// stlds(t+1) after; one __syncthreads per K-step. TLP across ~4 blocks/CU is
// the latency-hiding mechanism (m114), not intra-wave pipelining.
#define LDREGS(AR, ARF, BR, kb_) do {                                                    \
    int kb = (kb_);                                                                       \
    if constexpr (ABF) {                                                                  \
      _Pragma("unroll") for (int i = 0; i < AI; ++i) {                                    \
        int idx = tid + i * 256, r = idx / (BK / 8), c = (idx % (BK / 8)) * 8;            \
        AR[i] = *(const u16x8*)&((const unsigned short*)Ag)[(long)(m0 + r) * lda + kb + c]; \
      }                                                                                   \
    } else {                                                                              \
      _Pragma("unroll") for (int i = 0; i < AIF; ++i) {                                   \
        int idx = tid + i * 256, r = idx / (BK / 4), c = (idx % (BK / 4)) * 4;            \
        ARF[i] = *(const f32x4*)&((const float*)Ag)[(long)(m0 + r) * lda + kb + c];       \
      }                                                                                   \
    }                                                                                     \
    _Pragma("unroll") for (int i = 0; i < BI; ++i) {                                      \
      int idx = tid + i * 256, r = idx / (BK / 4), c = (idx % (BK / 4)) * 4;              \
      BR[i] = *(const f32x4*)&Bg[(long)(n0 + r) * ldb + kb + c];                          \
    }                                                                                     \
  } while (0)

#define STLDS(AR, ARF, BR, buf_) do {                                                    \
    unsigned short* As_ = lds + (buf_) * BUF;                                             \
    unsigned short* Bs_ = As_ + BM * LDT;                                                 \
    if constexpr (ABF) {                                                                  \
      _Pragma("unroll") for (int i = 0; i < AI; ++i) {                                    \
        int idx = tid + i * 256, r = idx / (BK / 8), c = (idx % (BK / 8)) * 8;            \
        *(u16x8*)&As_[r * LDT + c] = AR[i];                                               \
      }                                                                                   \
    } else {                                                                              \
      _Pragma("unroll") for (int i = 0; i < AIF; ++i) {                                   \
        int idx = tid + i * 256, r = idx / (BK / 4), c = (idx % (BK / 4)) * 4;            \
        u32x2 o; o[0] = pk2bf(ARF[i][0], ARF[i][1]); o[1] = pk2bf(ARF[i][2], ARF[i][3]); \
        *(u32x2*)&As_[r * LDT + c] = o;                                                   \
      }                                                                                   \
    }                                                                                     \
    _Pragma("unroll") for (int i = 0; i < BI; ++i) {                                      \
      int idx = tid + i * 256, r = idx / (BK / 4), c = (idx % (BK / 4)) * 4;              \
      u32x2 o; o[0] = pk2bf(BR[i][0], BR[i][1]); o[1] = pk2bf(BR[i][2], BR[i][3]);       \
      *(u32x2*)&Bs_[r * LDT + c] = o;                                                     \
    }                                                                                     \
  } while (0)

#define COMPUTE(buf_) do {                                                                \
    const unsigned short* As_ = lds + (buf_) * BUF;                                       \
    const unsigned short* Bs_ = As_ + BM * LDT;                                           \
    _Pragma("unroll") for (int kk = 0; kk < BK; kk += 32) {                               \
      int kr = kk + lhi * 8;                                                              \
      bf16x8 af[MI], bfr[NF];                                                             \
      _Pragma("unroll") for (int mi = 0; mi < MI; ++mi)                                   \
        af[mi] = *(const bf16x8*)&As_[(wm * (BM / 2) + mi * 16 + llo) * LDT + kr];        \
      _Pragma("unroll") for (int ni = 0; ni < NF; ++ni)                                   \
        bfr[ni] = *(const bf16x8*)&Bs_[(wn * 16 * NF + ni * 16 + llo) * LDT + kr];        \
      _Pragma("unroll") for (int mi = 0; mi < MI; ++mi)                                   \
        _Pragma("unroll") for (int ni = 0; ni < NF; ++ni)                                 \
          acc[mi * NF + ni] = __builtin_amdgcn_mfma_f32_16x16x32_bf16(                    \
              af[mi], bfr[ni], acc[mi * NF + ni], 0, 0, 0);                               \
    }                                                                                     \
  } while (0)

// requires nt = (k1-k0)/BK >= 2
template<int BM, int BN, int BK, bool ABF>
__device__ __forceinline__ void gemmMN(const void* Ag, int lda, const float* Bg, int ldb,
                                       int m0, int n0, int k0, int k1, unsigned short* lds,
                                       f32x4* acc) {
  constexpr int NF = BN / 32;
  constexpr int MI = BM / 32;
  constexpr int LDT = BK + 8;
  constexpr int BUF = (BM + BN) * LDT;
  constexpr int AI  = ABF ? (BM * BK / 2048) : 1;  // bf16 A: u16x8 pieces
  constexpr int AIF = ABF ? 1 : (BM * BK / 1024);  // f32  A: f32x4 pieces
  constexpr int BI  = BN * BK / 1024;              // f32  B: f32x4 pieces
  const int tid = threadIdx.x, lane = tid & 63, wave = tid >> 6;
  const int wm = wave >> 1, wn = wave & 1, llo = lane & 15, lhi = lane >> 4;

  u16x8 ar0[AI], ar1[AI];
  f32x4 arf0[AIF], arf1[AIF];
  f32x4 br0[BI], br1[BI];

  const int nt = (k1 - k0) / BK;
  LDREGS(ar0, arf0, br0, k0);
  LDREGS(ar1, arf1, br1, k0 + BK);
  STLDS(ar0, arf0, br0, 0);
  __syncthreads();
  int t = 0;
  while (true) {
    if (t + 2 < nt) LDREGS(ar0, arf0, br0, k0 + (t + 2) * BK);
    COMPUTE(0);
    if (t + 1 < nt) STLDS(ar1, arf1, br1, 1);
    __syncthreads();
    if (++t == nt) break;
    if (t + 2 < nt) LDREGS(ar1, arf1, br1, k0 + (t + 2) * BK);
    COMPUTE(1);
    if (t + 1 < nt) STLDS(ar0, arf0, br0, 0);
    __syncthreads();
    if (++t == nt) break;
  }
}

// ---------------- K01: RMSNorm + zero xz/proj + copy hs -> outp ----------------
__global__ __launch_bounds__(256) void k01_prep(const float* __restrict__ hs,
                                                const float* __restrict__ nw,
                                                unsigned short* __restrict__ normed,
                                                float* __restrict__ outp,
                                                float* __restrict__ xz,
                                                float* __restrict__ proj) {
  int blk = blockIdx.x, tid = threadIdx.x;
  int t = blk * 256 + tid;  // 0..262143
  f32x4 z = {};
  *(f32x4*)&xz[t * 4] = z;
  if (t < 65536) *(f32x4*)&outp[t * 4] = *(const f32x4*)&hs[t * 4];
  if (t < 5120) *(f32x4*)&proj[t * 4] = z;
  if (blk < 128) {
    int b = blk;
    const float* xr = hs + (long)b * DM;
    f32x4 v0 = *(const f32x4*)&xr[tid * 4];
    f32x4 v1 = *(const f32x4*)&xr[(tid + 256) * 4];
    float ss = v0[0]*v0[0] + v0[1]*v0[1] + v0[2]*v0[2] + v0[3]*v0[3]
             + v1[0]*v1[0] + v1[1]*v1[1] + v1[2]*v1[2] + v1[3]*v1[3];
    for (int off = 32; off; off >>= 1) ss += __shfl_xor(ss, off);
    __shared__ float red[4];
    if ((tid & 63) == 0) red[tid >> 6] = ss;
    __syncthreads();
    ss = red[0] + red[1] + red[2] + red[3];
    float rstd = rsqrtf(ss * (1.f / DM) + 1e-5f);
    f32x4 w0 = *(const f32x4*)&nw[tid * 4];
    f32x4 w1 = *(const f32x4*)&nw[(tid + 256) * 4];
    u32x2 o0, o1;
    o0[0] = pk2bf(v0[0] * rstd * w0[0], v0[1] * rstd * w0[1]);
    o0[1] = pk2bf(v0[2] * rstd * w0[2], v0[3] * rstd * w0[3]);
    o1[0] = pk2bf(v1[0] * rstd * w1[0], v1[1] * rstd * w1[1]);
    o1[1] = pk2bf(v1[2] * rstd * w1[2], v1[3] * rstd * w1[3]);
    *(u32x2*)&normed[(long)b * DM + tid * 4] = o0;
    *(u32x2*)&normed[(long)b * DM + (tid + 256) * 4] = o1;
  }
}

// ---------------- K2: in_proj GEMM (128x8192x2048), BK=32, split-K=8 ----------------
__global__ __launch_bounds__(256, 4) void k2_inproj(const unsigned short* __restrict__ normed,
                                                    const float* __restrict__ W,
                                                    float* __restrict__ xz) {
  __shared__ unsigned short lds[2 * (128 + 64) * 40];  // 30.7 KB -> 4+ blocks/CU
  f32x4 acc[8] = {};
  int bn = blockIdx.x, sk = blockIdx.y;
  gemmMN<128, 64, 32, true>(normed, DM, W, DM, 0, bn * 64, sk * 256, sk * 256 + 256, lds, acc);
  int tid = threadIdx.x, lane = tid & 63, wave = tid >> 6, wm = wave >> 1, wn = wave & 1;
  int llo = lane & 15, lhi = lane >> 4;
#pragma unroll
  for (int mi = 0; mi < 4; ++mi)
#pragma unroll
    for (int ni = 0; ni < 2; ++ni)
#pragma unroll
      for (int r = 0; r < 4; ++r) {
        int b = wm * 64 + mi * 16 + lhi * 4 + r;
        int n = bn * 64 + wn * 32 + ni * 16 + llo;
        atomicAdd(&xz[(long)b * 8192 + n], acc[mi * 2 + ni][r]);
      }
}

// ---------------- E2: conv + SiLU epilogue ----------------
__global__ __launch_bounds__(256) void e2_conv(const float* __restrict__ xz,
                                               const float* __restrict__ conv_state,
                                               const float* __restrict__ conv_w,
                                               const float* __restrict__ conv_b,
                                               float* __restrict__ out_ncs,
                                               float* __restrict__ xact_f,
                                               unsigned short* __restrict__ xact_b,
                                               unsigned short* __restrict__ szb) {
  int p = blockIdx.x * 256 + threadIdx.x;  // (b,n) pair, n fastest
  int b = p >> 12, n = p & 4095;
  float xc = xz[(long)b * 8192 + n];
  float z  = xz[(long)b * 8192 + DI + n];
  const float* cs = conv_state + (long)p * 3;
  float c0 = cs[0], c1 = cs[1], c2 = cs[2];
  f32x4 cw = *(const f32x4*)&conv_w[n * 4];
  float xs = c0 * cw[0] + c1 * cw[1] + c2 * cw[2] + xc * cw[3] + conv_b[n];
  float xa = xs * sigm(xs);
  float* ncs = out_ncs + (long)p * 3;
  ncs[0] = c1; ncs[1] = c2; ncs[2] = xc;
  xact_f[p] = xa;
  xact_b[p] = f2bf(xa);
  szb[p] = f2bf(z * sigm(z));
}

// ---------------- K3: x_proj GEMM (128x160x4096), BK=32, split-K=64 ----------------
__global__ __launch_bounds__(256, 4) void k3_xproj(const unsigned short* __restrict__ xact_b,
                                                   const float* __restrict__ XW,
                                                   float* __restrict__ proj) {
  __shared__ unsigned short lds[2 * (128 + 32) * 40];  // 25.6 KB
  f32x4 acc[4] = {};
  int bn = blockIdx.x, kc = blockIdx.y;
  gemmMN<128, 32, 32, true>(xact_b, DI, XW, DI, 0, bn * 32, kc * 64, kc * 64 + 64, lds, acc);
  int tid = threadIdx.x, lane = tid & 63, wave = tid >> 6, wm = wave >> 1, wn = wave & 1;
  int llo = lane & 15, lhi = lane >> 4;
  int n = bn * 32 + wn * 16 + llo;
#pragma unroll
  for (int mi = 0; mi < 4; ++mi)
#pragma unroll
    for (int r = 0; r < 4; ++r) {
      int b = wm * 64 + mi * 16 + lhi * 4 + r;
      atomicAdd(&proj[b * 160 + n], acc[mi][r]);
    }
}

// ---------------- K45: dt GEMM (32x32 tile, K=128) + softplus + SSM + y*silu(z) ----------------
__global__ __launch_bounds__(256) void k45_dtssm(const float* __restrict__ proj,
                                                 const float* __restrict__ DW,
                                                 const float* __restrict__ dtb,
                                                 const float* __restrict__ A_log,
                                                 const float* __restrict__ Dp,
                                                 const float* __restrict__ ssm,
                                                 const float* __restrict__ xact_f,
                                                 const unsigned short* __restrict__ szb,
                                                 float* __restrict__ out_nss,
                                                 unsigned short* __restrict__ yz_b) {
  __shared__ unsigned short lds[2 * (32 + 32) * 40];  // 10.2 KB
  f32x4 acc[1] = {};
  int nb = blockIdx.x, mb = blockIdx.y;
  gemmMN<32, 32, 32, false>(proj, 160, DW, 128, mb * 32, nb * 32, 0, 128, lds, acc);
  int tid = threadIdx.x, lane = tid & 63, wave = tid >> 6, wm = wave >> 1, wn = wave & 1;
  int llo = lane & 15, lhi = lane >> 4;
  int n = nb * 32 + wn * 16 + llo;
  float dtbn = dtb[n], Dn = Dp[n];
  f32x4 Al0 = *(const f32x4*)&A_log[n * 16];
  f32x4 Al1 = *(const f32x4*)&A_log[n * 16 + 4];
  f32x4 Al2 = *(const f32x4*)&A_log[n * 16 + 8];
  f32x4 Al3 = *(const f32x4*)&A_log[n * 16 + 12];
  float aS[16];
#pragma unroll
  for (int j = 0; j < 4; ++j) {
    aS[j] = -__expf(Al0[j]); aS[4 + j] = -__expf(Al1[j]);
    aS[8 + j] = -__expf(Al2[j]); aS[12 + j] = -__expf(Al3[j]);
  }
#pragma unroll
  for (int r = 0; r < 4; ++r) {
    int b = mb * 32 + wm * 16 + lhi * 4 + r;
    long p = (long)b * DI + n;
    float v = acc[0][r] + dtbn;
    float dtv = (v > 20.f) ? v : log1pf(__expf(v));
    float xa = xact_f[p];
    const float* Bp = proj + b * 160 + 128;
    const float* Cp = proj + b * 160 + 144;
    const float* sp = ssm + p * 16;
    float* np = out_nss + p * 16;
    float y = 0.f;
#pragma unroll
    for (int q = 0; q < 4; ++q) {
      f32x4 sv = *(const f32x4*)&sp[q * 4];
      f32x4 Bv = *(const f32x4*)&Bp[q * 4];
      f32x4 Cv = *(const f32x4*)&Cp[q * 4];
      f32x4 nv;
#pragma unroll
      for (int j = 0; j < 4; ++j) {
        float dA = __expf(dtv * aS[q * 4 + j]);
        nv[j] = sv[j] * dA + dtv * Bv[j] * xa;
        y += nv[j] * Cv[j];
      }
      *(f32x4*)&np[q * 4] = nv;
    }
    yz_b[p] = f2bf((y + Dn * xa) * bf2f(szb[p]));
  }
}

// ---------------- K5: out_proj GEMM (128x2048x4096), BK=32, split-K=16 ----------------
__global__ __launch_bounds__(256, 4) void k5_outproj(const unsigned short* __restrict__ yz_b,
                                                     const float* __restrict__ OW,
                                                     float* __restrict__ outp) {
  __shared__ unsigned short lds[2 * (128 + 32) * 40];  // 25.6 KB
  f32x4 acc[4] = {};
  int bn = blockIdx.x, sk = blockIdx.y;
  gemmMN<128, 32, 32, true>(yz_b, DI, OW, DI, 0, bn * 32, sk * 256, sk * 256 + 256, lds, acc);
  int tid = threadIdx.x, lane = tid & 63, wave = tid >> 6, wm = wave >> 1, wn = wave & 1;
  int llo = lane & 15, lhi = lane >> 4;
  int n = bn * 32 + wn * 16 + llo;
#pragma unroll
  for (int mi = 0; mi < 4; ++mi)
#pragma unroll
    for (int r = 0; r < 4; ++r) {
      int b = wm * 64 + mi * 16 + lhi * 4 + r;
      atomicAdd(&outp[(long)b * DM + n], acc[mi][r]);
    }
}

extern "C" void kernel_launch(void* const* d_in, const int* in_sizes, int n_in, void* d_out,
                              int out_size, void* d_ws, size_t ws_size, hipStream_t stream) {
  const float* hs         = (const float*)d_in[0];
  const float* conv_state = (const float*)d_in[1];
  const float* ssm        = (const float*)d_in[2];
  const float* norm_w     = (const float*)d_in[3];
  const float* in_proj_w  = (const float*)d_in[4];
  const float* conv_w     = (const float*)d_in[5];
  const float* conv_b     = (const float*)d_in[6];
  const float* x_proj_w   = (const float*)d_in[7];
  const float* dt_proj_w  = (const float*)d_in[8];
  const float* dt_proj_b  = (const float*)d_in[9];
  const float* A_log      = (const float*)d_in[10];
  const float* Dp         = (const float*)d_in[11];
  const float* out_proj_w = (const float*)d_in[12];

  float* outp    = (float*)d_out;               // (128,1,2048)
  float* out_ncs = outp + 262144;               // (128,4096,3)
  float* out_nss = outp + 262144 + 1572864;     // (128,4096,16)

  char* ws = (char*)d_ws;
  unsigned short* normed = (unsigned short*)(ws);             // 128x2048 bf16
  float*          xz     = (float*)(ws + 2097152);            // 128x8192 f32
  unsigned short* yz_b   = (unsigned short*)(ws + 2097152);   // 128x4096 bf16 (aliases xz, dead)
  float*          xact_f = (float*)(ws + 6291456);            // 128x4096 f32
  unsigned short* xact_b = (unsigned short*)(ws + 8388608);   // 128x4096 bf16
  unsigned short* szb    = (unsigned short*)(ws + 9437184);   // 128x4096 bf16 silu(z)
  float*          proj   = (float*)(ws + 10485760);           // 128x160 f32

  hipLaunchKernelGGL(k01_prep, dim3(1024), dim3(256), 0, stream, hs, norm_w, normed, outp, xz, proj);
  hipLaunchKernelGGL(k2_inproj, dim3(128, 8), dim3(256), 0, stream, normed, in_proj_w, xz);
  hipLaunchKernelGGL(e2_conv, dim3(2048), dim3(256), 0, stream, xz, conv_state, conv_w, conv_b,
                     out_ncs, xact_f, xact_b, szb);
  hipLaunchKernelGGL(k3_xproj, dim3(5, 64), dim3(256), 0, stream, xact_b, x_proj_w, proj);
  hipLaunchKernelGGL(k45_dtssm, dim3(128, 4), dim3(256), 0, stream, proj, dt_proj_w, dt_proj_b,
                     A_log, Dp, ssm, xact_f, szb, out_nss, yz_b);
  hipLaunchKernelGGL(k5_outproj, dim3(64, 16), dim3(256), 0, stream, yz_b, out_proj_w, outp);
}

// Round 10
// 77.652 us; speedup vs baseline: 1.2622x; 1.2622x over previous
//
#include <hip/hip_runtime.h>

typedef __attribute__((ext_vector_type(8))) short bf16x8;
typedef __attribute__((ext_vector_type(4))) float f32x4;
typedef __attribute__((ext_vector_type(8))) unsigned short u16x8;
typedef __attribute__((ext_vector_type(2))) unsigned u32x2;

#define DM 2048
#define DI 4096
#define BATCH 128

__device__ __forceinline__ unsigned short f2bf(float f) {
  union { float f; unsigned u; } v; v.f = f;
  unsigned r = v.u + 0x7FFFu + ((v.u >> 16) & 1u);
  return (unsigned short)(r >> 16);
}
__device__ __forceinline__ float bf2f(unsigned short u) {
  union { unsigned u; float f; } v; v.u = (unsigned)u << 16; return v.f;
}
// packed f32x2 -> bf16x2 (1 VALU inst, HW RNE)
__device__ __forceinline__ unsigned pk2bf(float lo, float hi) {
  unsigned r;
  asm("v_cvt_pk_bf16_f32 %0, %1, %2" : "=v"(r) : "v"(lo), "v"(hi));
  return r;
}
__device__ __forceinline__ float sigm(float x) { return 1.f / (1.f + __expf(-x)); }

constexpr int BK = 64;
constexpr int LDT = BK + 8;

// ---- depth-2 software-pipelined GEMM (R4/R6-proven), 256 thr = 4 waves (2M x 2N) ----
// NO atomics anywhere: epilogues write plain per-SK partial buffers.
#define LDREGS(AR, ARF, BR, kb_) do {                                                     \
    int kb = (kb_);                                                                       \
    if constexpr (ABF) {                                                                  \
      _Pragma("unroll") for (int i = 0; i < BM / 32; ++i) {                               \
        int idx = tid + i * 256, r = idx >> 3, c = (idx & 7) * 8;                         \
        AR[i] = *(const u16x8*)&((const unsigned short*)Ag)[(long)(m0 + r) * lda + kb + c]; \
      }                                                                                   \
    } else {                                                                              \
      _Pragma("unroll") for (int i = 0; i < BM / 16; ++i) {                               \
        int idx = tid + i * 256, r = idx >> 4, c = (idx & 15) * 4;                        \
        ARF[i] = *(const f32x4*)&((const float*)Ag)[(long)(m0 + r) * lda + kb + c];       \
      }                                                                                   \
    }                                                                                     \
    _Pragma("unroll") for (int i = 0; i < BN / 16; ++i) {                                 \
      int idx = tid + i * 256, r = idx >> 4, c = (idx & 15) * 4;                          \
      BR[i] = *(const f32x4*)&Bg[(long)(n0 + r) * ldb + kb + c];                          \
    }                                                                                     \
  } while (0)

#define STLDS(AR, ARF, BR, buf_) do {                                                     \
    unsigned short* As_ = lds + (buf_) * BUF;                                             \
    unsigned short* Bs_ = As_ + BM * LDT;                                                 \
    if constexpr (ABF) {                                                                  \
      _Pragma("unroll") for (int i = 0; i < BM / 32; ++i) {                               \
        int idx = tid + i * 256, r = idx >> 3, c = (idx & 7) * 8;                         \
        *(u16x8*)&As_[r * LDT + c] = AR[i];                                               \
      }                                                                                   \
    } else {                                                                              \
      _Pragma("unroll") for (int i = 0; i < BM / 16; ++i) {                               \
        int idx = tid + i * 256, r = idx >> 4, c = (idx & 15) * 4;                        \
        u32x2 o; o[0] = pk2bf(ARF[i][0], ARF[i][1]); o[1] = pk2bf(ARF[i][2], ARF[i][3]); \
        *(u32x2*)&As_[r * LDT + c] = o;                                                   \
      }                                                                                   \
    }                                                                                     \
    _Pragma("unroll") for (int i = 0; i < BN / 16; ++i) {                                 \
      int idx = tid + i * 256, r = idx >> 4, c = (idx & 15) * 4;                          \
      u32x2 o; o[0] = pk2bf(BR[i][0], BR[i][1]); o[1] = pk2bf(BR[i][2], BR[i][3]);       \
      *(u32x2*)&Bs_[r * LDT + c] = o;                                                     \
    }                                                                                     \
  } while (0)

#define COMPUTE(buf_) do {                                                                \
    const unsigned short* As_ = lds + (buf_) * BUF;                                       \
    const unsigned short* Bs_ = As_ + BM * LDT;                                           \
    _Pragma("unroll") for (int kk = 0; kk < BK; kk += 32) {                               \
      int kr = kk + lhi * 8;                                                              \
      bf16x8 af[MI], bfr[NF];                                                             \
      _Pragma("unroll") for (int mi = 0; mi < MI; ++mi)                                   \
        af[mi] = *(const bf16x8*)&As_[(wm * (BM / 2) + mi * 16 + llo) * LDT + kr];        \
      _Pragma("unroll") for (int ni = 0; ni < NF; ++ni)                                   \
        bfr[ni] = *(const bf16x8*)&Bs_[(wn * 16 * NF + ni * 16 + llo) * LDT + kr];        \
      _Pragma("unroll") for (int mi = 0; mi < MI; ++mi)                                   \
        _Pragma("unroll") for (int ni = 0; ni < NF; ++ni)                                 \
          acc[mi * NF + ni] = __builtin_amdgcn_mfma_f32_16x16x32_bf16(                    \
              af[mi], bfr[ni], acc[mi * NF + ni], 0, 0, 0);                               \
    }                                                                                     \
  } while (0)

// requires nt = (k1-k0)/BK >= 2
template<int BM, int BN, bool ABF>
__device__ __forceinline__ void gemmMN(const void* Ag, int lda, const float* Bg, int ldb,
                                       int m0, int n0, int k0, int k1, unsigned short* lds,
                                       f32x4* acc) {
  constexpr int NF = BN / 32;
  constexpr int MI = BM / 32;
  constexpr int BUF = (BM + BN) * LDT;
  const int tid = threadIdx.x, lane = tid & 63, wave = tid >> 6;
  const int wm = wave >> 1, wn = wave & 1, llo = lane & 15, lhi = lane >> 4;

  u16x8 ar0[ABF ? BM / 32 : 1], ar1[ABF ? BM / 32 : 1];
  f32x4 arf0[ABF ? 1 : BM / 16], arf1[ABF ? 1 : BM / 16];
  f32x4 br0[BN / 16], br1[BN / 16];

  const int nt = (k1 - k0) / BK;
  LDREGS(ar0, arf0, br0, k0);
  LDREGS(ar1, arf1, br1, k0 + BK);
  STLDS(ar0, arf0, br0, 0);
  __syncthreads();
  int t = 0;
  while (true) {
    if (t + 2 < nt) LDREGS(ar0, arf0, br0, k0 + (t + 2) * BK);
    COMPUTE(0);
    if (t + 1 < nt) STLDS(ar1, arf1, br1, 1);
    __syncthreads();
    if (++t == nt) break;
    if (t + 2 < nt) LDREGS(ar1, arf1, br1, k0 + (t + 2) * BK);
    COMPUTE(1);
    if (t + 1 < nt) STLDS(ar0, arf0, br0, 0);
    __syncthreads();
    if (++t == nt) break;
  }
}

// ---------------- K1: RMSNorm -> normed (bf16) ----------------
__global__ __launch_bounds__(256) void k1_rmsnorm(const float* __restrict__ hs,
                                                  const float* __restrict__ nw,
                                                  unsigned short* __restrict__ normed) {
  int b = blockIdx.x, tid = threadIdx.x;
  const float* xr = hs + (long)b * DM;
  f32x4 v0 = *(const f32x4*)&xr[tid * 4];
  f32x4 v1 = *(const f32x4*)&xr[(tid + 256) * 4];
  float ss = v0[0]*v0[0] + v0[1]*v0[1] + v0[2]*v0[2] + v0[3]*v0[3]
           + v1[0]*v1[0] + v1[1]*v1[1] + v1[2]*v1[2] + v1[3]*v1[3];
  for (int off = 32; off; off >>= 1) ss += __shfl_xor(ss, off);
  __shared__ float red[4];
  if ((tid & 63) == 0) red[tid >> 6] = ss;
  __syncthreads();
  ss = red[0] + red[1] + red[2] + red[3];
  float rstd = rsqrtf(ss * (1.f / DM) + 1e-5f);
  f32x4 w0 = *(const f32x4*)&nw[tid * 4];
  f32x4 w1 = *(const f32x4*)&nw[(tid + 256) * 4];
  u32x2 o0, o1;
  o0[0] = pk2bf(v0[0] * rstd * w0[0], v0[1] * rstd * w0[1]);
  o0[1] = pk2bf(v0[2] * rstd * w0[2], v0[3] * rstd * w0[3]);
  o1[0] = pk2bf(v1[0] * rstd * w1[0], v1[1] * rstd * w1[1]);
  o1[1] = pk2bf(v1[2] * rstd * w1[2], v1[3] * rstd * w1[3]);
  *(u32x2*)&normed[(long)b * DM + tid * 4] = o0;
  *(u32x2*)&normed[(long)b * DM + (tid + 256) * 4] = o1;
}

// ---------------- K2: in_proj GEMM (128x8192x2048), SK=4, PLAIN-STORE partials ----------------
__global__ __launch_bounds__(256) void k2_inproj(const unsigned short* __restrict__ normed,
                                                 const float* __restrict__ W,
                                                 float* __restrict__ xzp) {
  __shared__ unsigned short lds[2 * (128 + 64) * LDT];
  f32x4 acc[8] = {};
  int bn = blockIdx.x, sk = blockIdx.y;
  gemmMN<128, 64, true>(normed, DM, W, DM, 0, bn * 64, sk * 512, sk * 512 + 512, lds, acc);
  int tid = threadIdx.x, lane = tid & 63, wave = tid >> 6, wm = wave >> 1, wn = wave & 1;
  int llo = lane & 15, lhi = lane >> 4;
  float* dst = xzp + (long)sk * (BATCH * 8192);
#pragma unroll
  for (int mi = 0; mi < 4; ++mi)
#pragma unroll
    for (int ni = 0; ni < 2; ++ni)
#pragma unroll
      for (int r = 0; r < 4; ++r) {
        int b = wm * 64 + mi * 16 + lhi * 4 + r;
        int n = bn * 64 + wn * 32 + ni * 16 + llo;
        dst[(long)b * 8192 + n] = acc[mi * 2 + ni][r];
      }
}

// ---------------- E2: reduce xz partials + conv + SiLU ----------------
__global__ __launch_bounds__(256) void e2_conv(const float* __restrict__ xzp,
                                               const float* __restrict__ conv_state,
                                               const float* __restrict__ conv_w,
                                               const float* __restrict__ conv_b,
                                               float* __restrict__ out_ncs,
                                               float* __restrict__ xact_f,
                                               unsigned short* __restrict__ xact_b,
                                               unsigned short* __restrict__ szb) {
  int p = blockIdx.x * 256 + threadIdx.x;  // (b,n) pair, n fastest
  int b = p >> 12, n = p & 4095;
  long base = (long)b * 8192 + n;
  float xc = 0.f, z = 0.f;
#pragma unroll
  for (int s = 0; s < 4; ++s) {
    xc += xzp[(long)s * (BATCH * 8192) + base];
    z  += xzp[(long)s * (BATCH * 8192) + base + DI];
  }
  const float* cs = conv_state + (long)p * 3;
  float c0 = cs[0], c1 = cs[1], c2 = cs[2];
  f32x4 cw = *(const f32x4*)&conv_w[n * 4];
  float xs = c0 * cw[0] + c1 * cw[1] + c2 * cw[2] + xc * cw[3] + conv_b[n];
  float xa = xs * sigm(xs);
  float* ncs = out_ncs + (long)p * 3;
  ncs[0] = c1; ncs[1] = c2; ncs[2] = xc;
  xact_f[p] = xa;
  xact_b[p] = f2bf(xa);
  szb[p] = f2bf(z * sigm(z));
}

// ---------------- K3: x_proj GEMM (128x160x4096), SK=32, PLAIN-STORE partials ----------------
__global__ __launch_bounds__(256) void k3_xproj(const unsigned short* __restrict__ xact_b,
                                                const float* __restrict__ XW,
                                                float* __restrict__ projp) {
  __shared__ unsigned short lds[2 * (128 + 32) * LDT];
  f32x4 acc[4] = {};
  int bn = blockIdx.x, kc = blockIdx.y;
  gemmMN<128, 32, true>(xact_b, DI, XW, DI, 0, bn * 32, kc * 128, kc * 128 + 128, lds, acc);
  int tid = threadIdx.x, lane = tid & 63, wave = tid >> 6, wm = wave >> 1, wn = wave & 1;
  int llo = lane & 15, lhi = lane >> 4;
  int n = bn * 32 + wn * 16 + llo;
  float* dst = projp + (long)kc * (BATCH * 160);
#pragma unroll
  for (int mi = 0; mi < 4; ++mi)
#pragma unroll
    for (int r = 0; r < 4; ++r) {
      int b = wm * 64 + mi * 16 + lhi * 4 + r;
      dst[b * 160 + n] = acc[mi][r];
    }
}

// ---------------- K3r: reduce proj partials (32 -> 1) ----------------
__global__ __launch_bounds__(256) void k3r_reduce(const float* __restrict__ projp,
                                                  float* __restrict__ proj) {
  int t = blockIdx.x * 256 + threadIdx.x;  // 5120 f32x4 quads
  f32x4 s = {};
#pragma unroll
  for (int k = 0; k < 32; ++k) {
    f32x4 v = *(const f32x4*)&projp[(long)k * (BATCH * 160) + t * 4];
    s[0] += v[0]; s[1] += v[1]; s[2] += v[2]; s[3] += v[3];
  }
  *(f32x4*)&proj[t * 4] = s;
}

// ---------------- K45: dt GEMM (32x32 tile, K=128) + softplus + SSM + y*silu(z) ----------------
__global__ __launch_bounds__(256) void k45_dtssm(const float* __restrict__ proj,
                                                 const float* __restrict__ DW,
                                                 const float* __restrict__ dtb,
                                                 const float* __restrict__ A_log,
                                                 const float* __restrict__ Dp,
                                                 const float* __restrict__ ssm,
                                                 const float* __restrict__ xact_f,
                                                 const unsigned short* __restrict__ szb,
                                                 float* __restrict__ out_nss,
                                                 unsigned short* __restrict__ yz_b) {
  __shared__ unsigned short lds[2 * (32 + 32) * LDT];
  f32x4 acc[1] = {};
  int nb = blockIdx.x, mb = blockIdx.y;
  gemmMN<32, 32, false>(proj, 160, DW, 128, mb * 32, nb * 32, 0, 128, lds, acc);
  int tid = threadIdx.x, lane = tid & 63, wave = tid >> 6, wm = wave >> 1, wn = wave & 1;
  int llo = lane & 15, lhi = lane >> 4;
  int n = nb * 32 + wn * 16 + llo;
  float dtbn = dtb[n], Dn = Dp[n];
  f32x4 Al0 = *(const f32x4*)&A_log[n * 16];
  f32x4 Al1 = *(const f32x4*)&A_log[n * 16 + 4];
  f32x4 Al2 = *(const f32x4*)&A_log[n * 16 + 8];
  f32x4 Al3 = *(const f32x4*)&A_log[n * 16 + 12];
  float aS[16];
#pragma unroll
  for (int j = 0; j < 4; ++j) {
    aS[j] = -__expf(Al0[j]); aS[4 + j] = -__expf(Al1[j]);
    aS[8 + j] = -__expf(Al2[j]); aS[12 + j] = -__expf(Al3[j]);
  }
#pragma unroll
  for (int r = 0; r < 4; ++r) {
    int b = mb * 32 + wm * 16 + lhi * 4 + r;
    long p = (long)b * DI + n;
    float v = acc[0][r] + dtbn;
    float dtv = (v > 20.f) ? v : log1pf(__expf(v));
    float xa = xact_f[p];
    const float* Bp = proj + b * 160 + 128;
    const float* Cp = proj + b * 160 + 144;
    const float* sp = ssm + p * 16;
    float* np = out_nss + p * 16;
    float y = 0.f;
#pragma unroll
    for (int q = 0; q < 4; ++q) {
      f32x4 sv = *(const f32x4*)&sp[q * 4];
      f32x4 Bv = *(const f32x4*)&Bp[q * 4];
      f32x4 Cv = *(const f32x4*)&Cp[q * 4];
      f32x4 nv;
#pragma unroll
      for (int j = 0; j < 4; ++j) {
        float dA = __expf(dtv * aS[q * 4 + j]);
        nv[j] = sv[j] * dA + dtv * Bv[j] * xa;
        y += nv[j] * Cv[j];
      }
      *(f32x4*)&np[q * 4] = nv;
    }
    yz_b[p] = f2bf((y + Dn * xa) * bf2f(szb[p]));
  }
}

// ---------------- K5: out_proj GEMM (128x2048x4096), SK=8, PLAIN-STORE partials ----------------
__global__ __launch_bounds__(256) void k5_outproj(const unsigned short* __restrict__ yz_b,
                                                  const float* __restrict__ OW,
                                                  float* __restrict__ op) {
  __shared__ unsigned short lds[2 * (128 + 32) * LDT];
  f32x4 acc[4] = {};
  int bn = blockIdx.x, sk = blockIdx.y;
  gemmMN<128, 32, true>(yz_b, DI, OW, DI, 0, bn * 32, sk * 512, sk * 512 + 512, lds, acc);
  int tid = threadIdx.x, lane = tid & 63, wave = tid >> 6, wm = wave >> 1, wn = wave & 1;
  int llo = lane & 15, lhi = lane >> 4;
  int n = bn * 32 + wn * 16 + llo;
  float* dst = op + (long)sk * (BATCH * DM);
#pragma unroll
  for (int mi = 0; mi < 4; ++mi)
#pragma unroll
    for (int r = 0; r < 4; ++r) {
      int b = wm * 64 + mi * 16 + lhi * 4 + r;
      dst[(long)b * DM + n] = acc[mi][r];
    }
}

// ---------------- K7: reduce out partials (8) + residual ----------------
__global__ __launch_bounds__(256) void k7_out(const float* __restrict__ op,
                                              const float* __restrict__ hs,
                                              float* __restrict__ outp) {
  int t = blockIdx.x * 256 + threadIdx.x;  // 65536 f32x4 quads
  f32x4 s = *(const f32x4*)&hs[t * 4];
#pragma unroll
  for (int k = 0; k < 8; ++k) {
    f32x4 v = *(const f32x4*)&op[(long)k * (BATCH * DM) + t * 4];
    s[0] += v[0]; s[1] += v[1]; s[2] += v[2]; s[3] += v[3];
  }
  *(f32x4*)&outp[t * 4] = s;
}

extern "C" void kernel_launch(void* const* d_in, const int* in_sizes, int n_in, void* d_out,
                              int out_size, void* d_ws, size_t ws_size, hipStream_t stream) {
  const float* hs         = (const float*)d_in[0];
  const float* conv_state = (const float*)d_in[1];
  const float* ssm        = (const float*)d_in[2];
  const float* norm_w     = (const float*)d_in[3];
  const float* in_proj_w  = (const float*)d_in[4];
  const float* conv_w     = (const float*)d_in[5];
  const float* conv_b     = (const float*)d_in[6];
  const float* x_proj_w   = (const float*)d_in[7];
  const float* dt_proj_w  = (const float*)d_in[8];
  const float* dt_proj_b  = (const float*)d_in[9];
  const float* A_log      = (const float*)d_in[10];
  const float* Dp         = (const float*)d_in[11];
  const float* out_proj_w = (const float*)d_in[12];

  float* outp    = (float*)d_out;               // (128,1,2048)
  float* out_ncs = outp + 262144;               // (128,4096,3)
  float* out_nss = outp + 262144 + 1572864;     // (128,4096,16)

  char* ws = (char*)d_ws;
  unsigned short* normed = (unsigned short*)(ws);              // 0.5MB
  float*          xact_f = (float*)(ws + (1l << 20));          // 2MB
  unsigned short* xact_b = (unsigned short*)(ws + (3l << 20)); // 1MB
  unsigned short* szb    = (unsigned short*)(ws + (4l << 20)); // 1MB  silu(z) bf16
  float*          proj   = (float*)(ws + (5l << 20));          // 80KB
  float*          projp  = (float*)(ws + (6l << 20));          // 32 x 80KB = 2.5MB
  float*          xzp    = (float*)(ws + (9l << 20));          // 4 x 4MB = 16MB
  float*          op     = (float*)(ws + (25l << 20));         // 8 x 1MB = 8MB
  unsigned short* yz_b   = (unsigned short*)(ws + (34l << 20));// 1MB

  hipLaunchKernelGGL(k1_rmsnorm, dim3(128), dim3(256), 0, stream, hs, norm_w, normed);
  hipLaunchKernelGGL(k2_inproj, dim3(128, 4), dim3(256), 0, stream, normed, in_proj_w, xzp);
  hipLaunchKernelGGL(e2_conv, dim3(2048), dim3(256), 0, stream, xzp, conv_state, conv_w, conv_b,
                     out_ncs, xact_f, xact_b, szb);
  hipLaunchKernelGGL(k3_xproj, dim3(5, 32), dim3(256), 0, stream, xact_b, x_proj_w, projp);
  hipLaunchKernelGGL(k3r_reduce, dim3(20), dim3(256), 0, stream, projp, proj);
  hipLaunchKernelGGL(k45_dtssm, dim3(128, 4), dim3(256), 0, stream, proj, dt_proj_w, dt_proj_b,
                     A_log, Dp, ssm, xact_f, szb, out_nss, yz_b);
  hipLaunchKernelGGL(k5_outproj, dim3(64, 8), dim3(256), 0, stream, yz_b, out_proj_w, op);
  hipLaunchKernelGGL(k7_out, dim3(256), dim3(256), 0, stream, op, hs, outp);
}